// Round 10
// baseline (599.333 us; speedup 1.0000x reference)
//
#include <hip/hip_runtime.h>
#include <hip/hip_bf16.h>

#define N_NODES  100000
#define N_EDGES  1600000
#define N_GRAPHS 256
#define F 64
#define NBUCK  782    // ceil(N_NODES/128), bucket = dst >> 7
#define CHUNK  4096   // edges per partition chunk
#define NCHUNK 391    // ceil(1.6M/4096)
#define GB     391    // ceil(N_NODES/256) gemm blocks (256 nodes/block)

// ======== atomic-free CSR build: two-level counting sort ========

__global__ __launch_bounds__(1024) void k_hist(const int* __restrict__ dst, int* __restrict__ hist) {
    __shared__ int lh[NBUCK];
    int tid = threadIdx.x, chunk = blockIdx.x;
    for (int j = tid; j < NBUCK; j += 1024) lh[j] = 0;
    __syncthreads();
    int e0 = chunk * CHUNK;
#pragma unroll
    for (int i = 0; i < CHUNK / 1024; i++) {
        int e = e0 + i * 1024 + tid;
        if (e < N_EDGES) atomicAdd(&lh[dst[e] >> 7], 1);
    }
    __syncthreads();
    for (int j = tid; j < NBUCK; j += 1024) hist[chunk * NBUCK + j] = lh[j];
}

__global__ __launch_bounds__(512) void k_colscan(int* __restrict__ hist, int* __restrict__ btot) {
    __shared__ int ts[512];
    int b = blockIdx.x, tid = threadIdx.x;
    int v = (tid < NCHUNK) ? hist[tid * NBUCK + b] : 0;
    ts[tid] = v;
    __syncthreads();
    int x = v;
    for (int off = 1; off < 512; off <<= 1) {
        int t = (tid >= off) ? ts[tid - off] : 0;
        __syncthreads();
        x += t; ts[tid] = x;
        __syncthreads();
    }
    if (tid < NCHUNK) hist[tid * NBUCK + b] = x - v;
    if (tid == 511) btot[b] = x;
}

// block 0: scan bucket totals -> base; block 1: graph-boundary binary search
__global__ __launch_bounds__(512) void k_bscan_gstart(const int* __restrict__ btot, int* __restrict__ base,
                                                      const int* __restrict__ batch, int* __restrict__ gstart) {
    if (blockIdx.x == 1) {
        int g = threadIdx.x;
        if (g > N_GRAPHS) return;
        int lo = 0, hi = N_NODES;
        while (lo < hi) {
            int mid = (lo + hi) >> 1;
            if (batch[mid] < g) lo = mid + 1; else hi = mid;
        }
        gstart[g] = lo;
        return;
    }
    __shared__ int ts[256];
    int tid = threadIdx.x;
    int v[4], loc[4], run = 0;
    if (tid < 256) {
#pragma unroll
        for (int k = 0; k < 4; k++) {
            int c = tid * 4 + k;
            v[k] = (c < NBUCK) ? btot[c] : 0;
            loc[k] = run; run += v[k];
        }
        ts[tid] = run;
    }
    __syncthreads();
    int x = run;
    for (int off = 1; off < 256; off <<= 1) {
        int t = (tid >= off && tid < 256) ? ts[tid - off] : 0;
        __syncthreads();
        if (tid < 256) { x += t; ts[tid] = x; }
        __syncthreads();
    }
    if (tid < 256) {
        int texcl = x - run;
#pragma unroll
        for (int k = 0; k < 4; k++) {
            int c = tid * 4 + k;
            if (c < NBUCK) base[c] = texcl + loc[k];
        }
        if (tid == 255) base[NBUCK] = x;
    }
}

// ---- FUSED: edge partition (blocks 0..NCHUNK-1) + GEMM1 x@W1 (blocks NCHUNK..NCHUNK+GB-1) ----
// GEMM1 is independent of the CSR build; fusing co-schedules the latency-bound
// scatter with dense FMA work instead of serializing them.
__global__ __launch_bounds__(256) void k_part_gemm1(
    const int* __restrict__ src, const int* __restrict__ dst, const float* __restrict__ ew,
    const int* __restrict__ hist, const int* __restrict__ base, long long* __restrict__ part,
    const float* __restrict__ X, const float* __restrict__ W, __hip_bfloat16* __restrict__ H) {
    constexpr int KC = 32;
    constexpr int XP = KC + 4;                       // 36-float pitch
    __shared__ float smem[256 * XP + KC * F];        // 45 KB, unioned
    const int tid = threadIdx.x;

    if (blockIdx.x < NCHUNK) {
        // ---------- partition ----------
        int* cursor = (int*)smem;                    // 782 ints
        int chunk = blockIdx.x;
        for (int j = tid; j < NBUCK; j += 256) cursor[j] = base[j] + hist[chunk * NBUCK + j];
        __syncthreads();
        int e0 = chunk * CHUNK;
#pragma unroll
        for (int i = 0; i < CHUNK / 256; i++) {
            int e = e0 + i * 256 + tid;
            if (e < N_EDGES) {
                int d = dst[e];
                int pos = atomicAdd(&cursor[d >> 7], 1);
                unsigned lo = (unsigned)src[e] | ((unsigned)(d & 127) << 17);
                long long rec = (long long)((unsigned long long)lo |
                                ((unsigned long long)__float_as_uint(ew[e]) << 32));
                part[pos] = rec;
            }
        }
        return;
    }

    // ---------- GEMM1: H = X[N,128] @ W[128,64], bf16 out ----------
    float* Xs = smem;
    float* Ws = smem + 256 * XP;
    const int fgrp = tid & 7;
    const int ngrp = tid >> 3;            // 0..31
    const int f0   = fgrp * 8;
    const int nb   = (blockIdx.x - NCHUNK) * 256;
    constexpr int K = 128;

    float acc[8][8];
#pragma unroll
    for (int i = 0; i < 8; i++)
#pragma unroll
        for (int j = 0; j < 8; j++) acc[i][j] = 0.0f;

    for (int kc = 0; kc < K; kc += KC) {
        if (kc) __syncthreads();
#pragma unroll
        for (int pass = 0; pass < 8; pass++) {
            int idx = tid + pass * 256;
            int r = idx >> 3, q = idx & 7;
            int gr = nb + r; if (gr >= N_NODES) gr = N_NODES - 1;
            float4 v = *(const float4*)&X[(size_t)gr * K + kc + q * 4];
            *(float4*)&Xs[r * XP + q * 4] = v;
        }
#pragma unroll
        for (int pass = 0; pass < 2; pass++) {
            int idx = tid + pass * 256;
            float4 v = *(const float4*)&W[(size_t)(kc + (idx >> 4)) * F + (idx & 15) * 4];
            *(float4*)&Ws[idx * 4] = v;
        }
        __syncthreads();
#pragma unroll
        for (int k = 0; k < KC; k += 4) {
            float4 wa[4], wb[4];
#pragma unroll
            for (int kk = 0; kk < 4; kk++) {
                wa[kk] = *(const float4*)&Ws[(k + kk) * F + f0];
                wb[kk] = *(const float4*)&Ws[(k + kk) * F + f0 + 4];
            }
#pragma unroll
            for (int i = 0; i < 8; i++) {
                float4 xv = *(const float4*)&Xs[(ngrp + 32 * i) * XP + k];
#pragma unroll
                for (int kk = 0; kk < 4; kk++) {
                    float xk = (kk == 0) ? xv.x : (kk == 1) ? xv.y : (kk == 2) ? xv.z : xv.w;
                    acc[i][0] = fmaf(xk, wa[kk].x, acc[i][0]);
                    acc[i][1] = fmaf(xk, wa[kk].y, acc[i][1]);
                    acc[i][2] = fmaf(xk, wa[kk].z, acc[i][2]);
                    acc[i][3] = fmaf(xk, wa[kk].w, acc[i][3]);
                    acc[i][4] = fmaf(xk, wb[kk].x, acc[i][4]);
                    acc[i][5] = fmaf(xk, wb[kk].y, acc[i][5]);
                    acc[i][6] = fmaf(xk, wb[kk].z, acc[i][6]);
                    acc[i][7] = fmaf(xk, wb[kk].w, acc[i][7]);
                }
            }
        }
    }
#pragma unroll
    for (int i = 0; i < 8; i++) {
        int gn = nb + ngrp + 32 * i;
        if (gn < N_NODES) {
            __hip_bfloat16 hb[8];
#pragma unroll
            for (int j = 0; j < 8; j++) hb[j] = __float2bfloat16(acc[i][j]);
            *(uint4*)&H[(size_t)gn * F + f0] = *(uint4*)hb;
        }
    }
}

// per-bucket pass 1: degrees (LDS float atomics) -> dinv_g, counts -> row_off
__global__ __launch_bounds__(512) void k_deg(const long long* __restrict__ part,
                                             const int* __restrict__ base,
                                             float* __restrict__ dinv_g, int* __restrict__ row_off) {
    __shared__ float fdeg[128];
    __shared__ int   cnt[128];
    __shared__ int   sc[128];
    int b = blockIdx.x, tid = threadIdx.x;
    if (tid < 128) { fdeg[tid] = 1.0f; cnt[tid] = 0; }   // 1.0 = self-loop weight
    __syncthreads();
    int e0 = base[b], e1 = base[b + 1];
    for (int k = e0 + tid; k < e1; k += 512) {
        long long rec = part[k];
        int d7 = ((int)rec >> 17) & 127;
        atomicAdd(&fdeg[d7], __uint_as_float((unsigned)(rec >> 32)));
        atomicAdd(&cnt[d7], 1);
    }
    __syncthreads();
    int myc = 0, x = 0;
    if (tid < 128) {
        int node = b * 128 + tid;
        if (node < N_NODES) dinv_g[node] = rsqrtf(fdeg[tid]);
        myc = cnt[tid]; x = myc; sc[tid] = x;
    }
    __syncthreads();
    for (int off = 1; off < 128; off <<= 1) {
        int t = (tid < 128 && tid >= off) ? sc[tid - off] : 0;
        __syncthreads();
        if (tid < 128) { x += t; sc[tid] = x; }
        __syncthreads();
    }
    if (tid < 128) {
        int node = b * 128 + tid;
        if (node < N_NODES) row_off[node] = e0 + (x - myc);
    }
    if (b == 0 && tid == 0) row_off[N_NODES] = N_EDGES;
}

// per-bucket pass 2: scatter esec = (src*128 byte-off, w*dinv[d]*dinv[src])
__global__ __launch_bounds__(512) void k_scat(const long long* __restrict__ part,
                                              const int* __restrict__ base,
                                              const float* __restrict__ dinv_g,
                                              const int* __restrict__ row_off,
                                              int2* __restrict__ esec) {
    __shared__ int   cursor[128];
    __shared__ float sdinv[128];
    int b = blockIdx.x, tid = threadIdx.x;
    if (tid < 128) {
        int node = b * 128 + tid;
        cursor[tid] = row_off[node < N_NODES ? node : N_NODES];
        sdinv[tid]  = dinv_g[node < N_NODES ? node : 0];
    }
    __syncthreads();
    int e0 = base[b], e1 = base[b + 1];
    for (int k = e0 + tid; k < e1; k += 512) {
        long long rec = part[k];
        int lo = (int)rec;
        int d7 = (lo >> 17) & 127;
        int s  = lo & 0x1FFFF;
        float w = __uint_as_float((unsigned)(rec >> 32));
        float coef = (w * sdinv[d7]) * dinv_g[s];
        int pos = atomicAdd(&cursor[d7], 1);
        esec[pos] = make_int2(s << 7, __float_as_int(coef));   // byte off: src*128 (bf16 row)
    }
    if (b == 0 && tid < 32) esec[N_EDGES + tid] = make_int2(0, 0);  // sentinels for agg overrun
}

// ---------------- GEMM (layers 2/3): H = X_bf16[N,64] @ W[64,64], bf16 out ----------------
template <int K>
__global__ __launch_bounds__(256) void k_gemm(const unsigned short* __restrict__ X,
                                              const float* __restrict__ W,
                                              __hip_bfloat16* __restrict__ H) {
    constexpr int KC = 32;
    constexpr int XP = KC + 4;
    __shared__ float Xs[256 * XP];
    __shared__ float Ws[KC * F];
    const int tid  = threadIdx.x;
    const int fgrp = tid & 7;
    const int ngrp = tid >> 3;
    const int f0   = fgrp * 8;
    const int nb   = blockIdx.x * 256;

    float acc[8][8];
#pragma unroll
    for (int i = 0; i < 8; i++)
#pragma unroll
        for (int j = 0; j < 8; j++) acc[i][j] = 0.0f;

    for (int kc = 0; kc < K; kc += KC) {
        if (kc) __syncthreads();
#pragma unroll
        for (int pass = 0; pass < 4; pass++) {
            int idx = tid + pass * 256;
            int r = idx >> 2, q = idx & 3;
            int gr = nb + r; if (gr >= N_NODES) gr = N_NODES - 1;
            uint4 v = *(const uint4*)&X[(size_t)gr * K + kc + q * 8];
            float* dp = &Xs[r * XP + q * 8];
            dp[0] = __uint_as_float(v.x << 16);
            dp[1] = __uint_as_float(v.x & 0xffff0000u);
            dp[2] = __uint_as_float(v.y << 16);
            dp[3] = __uint_as_float(v.y & 0xffff0000u);
            dp[4] = __uint_as_float(v.z << 16);
            dp[5] = __uint_as_float(v.z & 0xffff0000u);
            dp[6] = __uint_as_float(v.w << 16);
            dp[7] = __uint_as_float(v.w & 0xffff0000u);
        }
#pragma unroll
        for (int pass = 0; pass < 2; pass++) {
            int idx = tid + pass * 256;
            float4 v = *(const float4*)&W[(size_t)(kc + (idx >> 4)) * F + (idx & 15) * 4];
            *(float4*)&Ws[idx * 4] = v;
        }
        __syncthreads();
#pragma unroll
        for (int k = 0; k < KC; k += 4) {
            float4 wa[4], wb[4];
#pragma unroll
            for (int kk = 0; kk < 4; kk++) {
                wa[kk] = *(const float4*)&Ws[(k + kk) * F + f0];
                wb[kk] = *(const float4*)&Ws[(k + kk) * F + f0 + 4];
            }
#pragma unroll
            for (int i = 0; i < 8; i++) {
                float4 xv = *(const float4*)&Xs[(ngrp + 32 * i) * XP + k];
#pragma unroll
                for (int kk = 0; kk < 4; kk++) {
                    float xk = (kk == 0) ? xv.x : (kk == 1) ? xv.y : (kk == 2) ? xv.z : xv.w;
                    acc[i][0] = fmaf(xk, wa[kk].x, acc[i][0]);
                    acc[i][1] = fmaf(xk, wa[kk].y, acc[i][1]);
                    acc[i][2] = fmaf(xk, wa[kk].z, acc[i][2]);
                    acc[i][3] = fmaf(xk, wa[kk].w, acc[i][3]);
                    acc[i][4] = fmaf(xk, wb[kk].x, acc[i][4]);
                    acc[i][5] = fmaf(xk, wb[kk].y, acc[i][5]);
                    acc[i][6] = fmaf(xk, wb[kk].z, acc[i][6]);
                    acc[i][7] = fmaf(xk, wb[kk].w, acc[i][7]);
                }
            }
        }
    }
#pragma unroll
    for (int i = 0; i < 8; i++) {
        int gn = nb + ngrp + 32 * i;
        if (gn < N_NODES) {
            __hip_bfloat16 hb[8];
#pragma unroll
            for (int j = 0; j < 8; j++) hb[j] = __float2bfloat16(acc[i][j]);
            *(uint4*)&H[(size_t)gn * F + f0] = *(uint4*)hb;
        }
    }
}

// ---------------- aggregation: O = relu(b + dinv^2*H + sum_in c*H[src]) ----------------
// 4 nodes/wave x DUAL 8-edge windows = 8 independent gathers in flight per wave.
// Lane = (q = l>>3 edge slot, f8 = l&7 feat group); each gather is dwordx4 = one
// full 128B bf16 row per 8 lanes. Tail: index clamp to zeroed sentinels +
// per-window coefficient kill. Epilogue: shfl_xor reduce over q; q==0..3 write.
__global__ __launch_bounds__(256) void k_agg(const __hip_bfloat16* __restrict__ H,
                                             const int* __restrict__ row_off,
                                             const int2* __restrict__ esec,
                                             const float* __restrict__ dinv,
                                             const float* __restrict__ bias,
                                             __hip_bfloat16* __restrict__ O) {
    int wv   = threadIdx.x >> 6;
    int lane = threadIdx.x & 63;
    int np   = blockIdx.x * 16 + wv * 4;
    int q  = lane >> 3;
    int f8 = lane & 7;
    int r0 = __builtin_amdgcn_readfirstlane(row_off[np]);
    int r1 = __builtin_amdgcn_readfirstlane(row_off[np + 1]);
    int r2 = __builtin_amdgcn_readfirstlane(row_off[np + 2]);
    int r3 = __builtin_amdgcn_readfirstlane(row_off[np + 3]);
    int r4 = __builtin_amdgcn_readfirstlane(row_off[np + 4]);
    const char* Hbase = (const char*)H;

    float a[4][8];
#pragma unroll
    for (int n = 0; n < 4; n++)
#pragma unroll
        for (int u = 0; u < 8; u++) a[n][u] = 0.0f;

    int jb[4] = { r0 + q, r1 + q, r2 + q, r3 + q };
    int re[4] = { r1, r2, r3, r4 };
    int l0 = r1 - r0, l1 = r2 - r1, l2 = r3 - r2, l3 = r4 - r3;
    int ml = l0 > l1 ? l0 : l1;
    if (l2 > ml) ml = l2;
    if (l3 > ml) ml = l3;
    int iters = (ml + 15) >> 4;

    for (int it = 0; it < iters; it++) {
        int2 ev[8];
#pragma unroll
        for (int s = 0; s < 8; s++) {
            int jj = jb[s >> 1] + ((s & 1) << 3);
            int ii = jj < N_EDGES ? jj : N_EDGES;    // clamp into zeroed sentinels
            ev[s] = esec[ii];
        }
        uint4 h[8];
#pragma unroll
        for (int s = 0; s < 8; s++)
            h[s] = *(const uint4*)(Hbase + (unsigned)ev[s].x + (f8 << 4));
#pragma unroll
        for (int s = 0; s < 8; s++) {
            int n = s >> 1;
            int jj = jb[n] + ((s & 1) << 3);
            float c = (jj < re[n]) ? __int_as_float(ev[s].y) : 0.0f;
            a[n][0] = fmaf(c, __uint_as_float(h[s].x << 16),         a[n][0]);
            a[n][1] = fmaf(c, __uint_as_float(h[s].x & 0xffff0000u), a[n][1]);
            a[n][2] = fmaf(c, __uint_as_float(h[s].y << 16),         a[n][2]);
            a[n][3] = fmaf(c, __uint_as_float(h[s].y & 0xffff0000u), a[n][3]);
            a[n][4] = fmaf(c, __uint_as_float(h[s].z << 16),         a[n][4]);
            a[n][5] = fmaf(c, __uint_as_float(h[s].z & 0xffff0000u), a[n][5]);
            a[n][6] = fmaf(c, __uint_as_float(h[s].w << 16),         a[n][6]);
            a[n][7] = fmaf(c, __uint_as_float(h[s].w & 0xffff0000u), a[n][7]);
        }
#pragma unroll
        for (int n = 0; n < 4; n++) jb[n] += 16;
    }
#pragma unroll
    for (int m = 8; m < 64; m <<= 1) {
#pragma unroll
        for (int n = 0; n < 4; n++)
#pragma unroll
            for (int u = 0; u < 8; u++) a[n][u] += __shfl_xor(a[n][u], m);
    }
    if (q < 4) {
        int node = np + q;
        float av[8];
#pragma unroll
        for (int u = 0; u < 8; u++) {
            float t01 = (q & 1) ? a[1][u] : a[0][u];
            float t23 = (q & 1) ? a[3][u] : a[2][u];
            av[u] = (q & 2) ? t23 : t01;
        }
        float di = dinv[node];
        float di2 = di * di;
        uint4 hs = *(const uint4*)(Hbase + (size_t)node * 128 + (f8 << 4));
        float hv[8];
        hv[0] = __uint_as_float(hs.x << 16);
        hv[1] = __uint_as_float(hs.x & 0xffff0000u);
        hv[2] = __uint_as_float(hs.y << 16);
        hv[3] = __uint_as_float(hs.y & 0xffff0000u);
        hv[4] = __uint_as_float(hs.z << 16);
        hv[5] = __uint_as_float(hs.z & 0xffff0000u);
        hv[6] = __uint_as_float(hs.w << 16);
        hv[7] = __uint_as_float(hs.w & 0xffff0000u);
        const float4* bp = (const float4*)(bias + f8 * 8);
        float4 bv0 = bp[0], bv1 = bp[1];
        float r[8];
        r[0] = fmaxf(av[0] + bv0.x + di2 * hv[0], 0.0f);
        r[1] = fmaxf(av[1] + bv0.y + di2 * hv[1], 0.0f);
        r[2] = fmaxf(av[2] + bv0.z + di2 * hv[2], 0.0f);
        r[3] = fmaxf(av[3] + bv0.w + di2 * hv[3], 0.0f);
        r[4] = fmaxf(av[4] + bv1.x + di2 * hv[4], 0.0f);
        r[5] = fmaxf(av[5] + bv1.y + di2 * hv[5], 0.0f);
        r[6] = fmaxf(av[6] + bv1.z + di2 * hv[6], 0.0f);
        r[7] = fmaxf(av[7] + bv1.w + di2 * hv[7], 0.0f);
        __hip_bfloat16 hb[8];
#pragma unroll
        for (int u = 0; u < 8; u++) hb[u] = __float2bfloat16(r[u]);
        *(uint4*)&O[(size_t)node * F + f8 * 8] = *(uint4*)hb;
    }
}

// ---------------- fused mean-pool + final linear (bf16 input) ----------------
__global__ __launch_bounds__(256) void k_pool_linear(const __hip_bfloat16* __restrict__ H,
                                                     const int* __restrict__ gstart,
                                                     const float* __restrict__ Wl,
                                                     const float* __restrict__ bl,
                                                     float* __restrict__ out) {
    int g = blockIdx.x;
    int beg = gstart[g], end = gstart[g + 1];
    int lane = threadIdx.x & 63, wv = threadIdx.x >> 6;
    float acc = 0.0f;
    for (int r = beg + wv; r < end; r += 4)
        acc += __bfloat162float(H[(size_t)r * F + lane]);
    __shared__ float s[4][F];
    s[wv][lane] = acc;
    __syncthreads();
    if (wv == 0) {
        float tot = s[0][lane] + s[1][lane] + s[2][lane] + s[3][lane];
        float cntf = (float)(end - beg);
        float p = tot / fmaxf(cntf, 1.0f);
        for (int c = 0; c < 10; c++) {
            float v = p * Wl[lane * 10 + c];
            for (int off = 32; off; off >>= 1) v += __shfl_down(v, off);
            if (lane == 0) out[g * 10 + c] = v + bl[c];
        }
    }
}

// ---------------- launch ----------------

extern "C" void kernel_launch(void* const* d_in, const int* in_sizes, int n_in,
                              void* d_out, int out_size, void* d_ws, size_t ws_size,
                              hipStream_t stream) {
    const float* x    = (const float*)d_in[0];
    const int*   ei   = (const int*)d_in[1];
    const float* ea   = (const float*)d_in[2];
    const int*   bat  = (const int*)d_in[3];
    const float* W1   = (const float*)d_in[4];
    const float* b1   = (const float*)d_in[5];
    const float* W2   = (const float*)d_in[6];
    const float* b2   = (const float*)d_in[7];
    const float* W3   = (const float*)d_in[8];
    const float* b3   = (const float*)d_in[9];
    const float* Wl   = (const float*)d_in[10];
    const float* bl   = (const float*)d_in[11];
    float* out = (float*)d_out;

    const int* src = ei;
    const int* dst = ei + N_EDGES;

    char* ws = (char*)d_ws;
    size_t off = 0;
    auto carve = [&](size_t bytes) {
        void* p = ws + off;
        off += (bytes + 255) & ~(size_t)255;
        return p;
    };
    // all buffers distinct now (part must not alias hbuf: GEMM1 writes hbuf
    // concurrently with the partition scatter inside the fused dispatch)
    float*          dinv    = (float*)carve(N_NODES * 4);
    int*            row_off = (int*)  carve((N_NODES + 1) * 4);
    int2*           esec    = (int2*) carve(((size_t)N_EDGES + 32) * 8);        // 12.8 MB
    __hip_bfloat16* hbuf    = (__hip_bfloat16*)carve((size_t)N_NODES * F * 2);  // 12.8 MB
    __hip_bfloat16* obuf    = (__hip_bfloat16*)carve((size_t)N_NODES * F * 2);  // 12.8 MB
    long long*      part    = (long long*)carve((size_t)N_EDGES * 8);           // 12.8 MB
    int*            hist    = (int*)  carve((size_t)NCHUNK * NBUCK * 4);        // 1.22 MB
    int*            btot    = (int*)  carve((NBUCK + 8) * 4);
    int*            base    = (int*)  carve((NBUCK + 8) * 4);
    int*            gstart  = (int*)  carve((N_GRAPHS + 1) * 4);
    (void)ws_size; (void)in_sizes; (void)n_in; (void)out_size;

    k_hist        <<<NCHUNK,      1024, 0, stream>>>(dst, hist);
    k_colscan     <<<NBUCK,       512,  0, stream>>>(hist, btot);
    k_bscan_gstart<<<2,           512,  0, stream>>>(btot, base, bat, gstart);
    k_part_gemm1  <<<NCHUNK + GB, 256,  0, stream>>>(src, dst, ea, hist, base, part,
                                                     x, W1, hbuf);
    k_deg         <<<NBUCK,       512,  0, stream>>>(part, base, dinv, row_off);
    k_scat        <<<NBUCK,       512,  0, stream>>>(part, base, dinv, row_off, esec);

    k_agg<<<N_NODES / 16, 256, 0, stream>>>(hbuf, row_off, esec, dinv, b1, obuf);
    k_gemm<64><<<GB, 256, 0, stream>>>((const unsigned short*)obuf, W2, hbuf);
    k_agg<<<N_NODES / 16, 256, 0, stream>>>(hbuf, row_off, esec, dinv, b2, obuf);
    k_gemm<64><<<GB, 256, 0, stream>>>((const unsigned short*)obuf, W3, hbuf);
    k_agg<<<N_NODES / 16, 256, 0, stream>>>(hbuf, row_off, esec, dinv, b3, obuf);

    k_pool_linear<<<N_GRAPHS, 256, 0, stream>>>(obuf, gstart, Wl, bl, out);
}

// Round 11
// 380.236 us; speedup vs baseline: 1.5762x; 1.5762x over previous
//
#include <hip/hip_runtime.h>
#include <hip/hip_bf16.h>

#define N_NODES  100000
#define N_EDGES  1600000
#define N_GRAPHS 256
#define F 64
#define NBUCK  782    // ceil(N_NODES/128), bucket = dst >> 7
#define CHUNK  4096   // edges per partition chunk
#define NCHUNK 391    // ceil(1.6M/4096)
#define GB     391    // ceil(N_NODES/256) gemm blocks (256 nodes/block)

// ======== atomic-free CSR build: two-level counting sort ========

__global__ __launch_bounds__(1024) void k_hist(const int* __restrict__ dst, int* __restrict__ hist) {
    __shared__ int lh[NBUCK];
    int tid = threadIdx.x, chunk = blockIdx.x;
    for (int j = tid; j < NBUCK; j += 1024) lh[j] = 0;
    __syncthreads();
    int e0 = chunk * CHUNK;
#pragma unroll
    for (int i = 0; i < CHUNK / 1024; i++) {
        int e = e0 + i * 1024 + tid;
        if (e < N_EDGES) atomicAdd(&lh[dst[e] >> 7], 1);
    }
    __syncthreads();
    for (int j = tid; j < NBUCK; j += 1024) hist[chunk * NBUCK + j] = lh[j];
}

__global__ __launch_bounds__(512) void k_colscan(int* __restrict__ hist, int* __restrict__ btot) {
    __shared__ int ts[512];
    int b = blockIdx.x, tid = threadIdx.x;
    int v = (tid < NCHUNK) ? hist[tid * NBUCK + b] : 0;
    ts[tid] = v;
    __syncthreads();
    int x = v;
    for (int off = 1; off < 512; off <<= 1) {
        int t = (tid >= off) ? ts[tid - off] : 0;
        __syncthreads();
        x += t; ts[tid] = x;
        __syncthreads();
    }
    if (tid < NCHUNK) hist[tid * NBUCK + b] = x - v;
    if (tid == 511) btot[b] = x;
}

// block 0: scan bucket totals -> base; block 1: graph-boundary binary search
__global__ __launch_bounds__(512) void k_bscan_gstart(const int* __restrict__ btot, int* __restrict__ base,
                                                      const int* __restrict__ batch, int* __restrict__ gstart) {
    if (blockIdx.x == 1) {
        int g = threadIdx.x;
        if (g > N_GRAPHS) return;
        int lo = 0, hi = N_NODES;
        while (lo < hi) {
            int mid = (lo + hi) >> 1;
            if (batch[mid] < g) lo = mid + 1; else hi = mid;
        }
        gstart[g] = lo;
        return;
    }
    __shared__ int ts[256];
    int tid = threadIdx.x;
    int v[4], loc[4], run = 0;
    if (tid < 256) {
#pragma unroll
        for (int k = 0; k < 4; k++) {
            int c = tid * 4 + k;
            v[k] = (c < NBUCK) ? btot[c] : 0;
            loc[k] = run; run += v[k];
        }
        ts[tid] = run;
    }
    __syncthreads();
    int x = run;
    for (int off = 1; off < 256; off <<= 1) {
        int t = (tid >= off && tid < 256) ? ts[tid - off] : 0;
        __syncthreads();
        if (tid < 256) { x += t; ts[tid] = x; }
        __syncthreads();
    }
    if (tid < 256) {
        int texcl = x - run;
#pragma unroll
        for (int k = 0; k < 4; k++) {
            int c = tid * 4 + k;
            if (c < NBUCK) base[c] = texcl + loc[k];
        }
        if (tid == 255) base[NBUCK] = x;
    }
}

// ---- FUSED: edge partition (blocks 0..NCHUNK-1) + GEMM1 x@W1 (blocks NCHUNK..) ----
__global__ __launch_bounds__(256) void k_part_gemm1(
    const int* __restrict__ src, const int* __restrict__ dst, const float* __restrict__ ew,
    const int* __restrict__ hist, const int* __restrict__ base, long long* __restrict__ part,
    const float* __restrict__ X, const float* __restrict__ W, __hip_bfloat16* __restrict__ H) {
    constexpr int KC = 32;
    constexpr int XP = KC + 4;                       // 36-float pitch
    __shared__ float smem[256 * XP + KC * F];        // 45 KB, unioned
    const int tid = threadIdx.x;

    if (blockIdx.x < NCHUNK) {
        // ---------- partition ----------
        int* cursor = (int*)smem;                    // 782 ints
        int chunk = blockIdx.x;
        for (int j = tid; j < NBUCK; j += 256) cursor[j] = base[j] + hist[chunk * NBUCK + j];
        __syncthreads();
        int e0 = chunk * CHUNK;
#pragma unroll
        for (int i = 0; i < CHUNK / 256; i++) {
            int e = e0 + i * 256 + tid;
            if (e < N_EDGES) {
                int d = dst[e];
                int pos = atomicAdd(&cursor[d >> 7], 1);
                unsigned lo = (unsigned)src[e] | ((unsigned)(d & 127) << 17);
                long long rec = (long long)((unsigned long long)lo |
                                ((unsigned long long)__float_as_uint(ew[e]) << 32));
                part[pos] = rec;
            }
        }
        return;
    }

    // ---------- GEMM1: H = X[N,128] @ W[128,64], bf16 out ----------
    float* Xs = smem;
    float* Ws = smem + 256 * XP;
    const int fgrp = tid & 7;
    const int ngrp = tid >> 3;            // 0..31
    const int f0   = fgrp * 8;
    const int nb   = (blockIdx.x - NCHUNK) * 256;
    constexpr int K = 128;

    float acc[8][8];
#pragma unroll
    for (int i = 0; i < 8; i++)
#pragma unroll
        for (int j = 0; j < 8; j++) acc[i][j] = 0.0f;

    for (int kc = 0; kc < K; kc += KC) {
        if (kc) __syncthreads();
#pragma unroll
        for (int pass = 0; pass < 8; pass++) {
            int idx = tid + pass * 256;
            int r = idx >> 3, q = idx & 7;
            int gr = nb + r; if (gr >= N_NODES) gr = N_NODES - 1;
            float4 v = *(const float4*)&X[(size_t)gr * K + kc + q * 4];
            *(float4*)&Xs[r * XP + q * 4] = v;
        }
#pragma unroll
        for (int pass = 0; pass < 2; pass++) {
            int idx = tid + pass * 256;
            float4 v = *(const float4*)&W[(size_t)(kc + (idx >> 4)) * F + (idx & 15) * 4];
            *(float4*)&Ws[idx * 4] = v;
        }
        __syncthreads();
#pragma unroll
        for (int k = 0; k < KC; k += 4) {
            float4 wa[4], wb[4];
#pragma unroll
            for (int kk = 0; kk < 4; kk++) {
                wa[kk] = *(const float4*)&Ws[(k + kk) * F + f0];
                wb[kk] = *(const float4*)&Ws[(k + kk) * F + f0 + 4];
            }
#pragma unroll
            for (int i = 0; i < 8; i++) {
                float4 xv = *(const float4*)&Xs[(ngrp + 32 * i) * XP + k];
#pragma unroll
                for (int kk = 0; kk < 4; kk++) {
                    float xk = (kk == 0) ? xv.x : (kk == 1) ? xv.y : (kk == 2) ? xv.z : xv.w;
                    acc[i][0] = fmaf(xk, wa[kk].x, acc[i][0]);
                    acc[i][1] = fmaf(xk, wa[kk].y, acc[i][1]);
                    acc[i][2] = fmaf(xk, wa[kk].z, acc[i][2]);
                    acc[i][3] = fmaf(xk, wa[kk].w, acc[i][3]);
                    acc[i][4] = fmaf(xk, wb[kk].x, acc[i][4]);
                    acc[i][5] = fmaf(xk, wb[kk].y, acc[i][5]);
                    acc[i][6] = fmaf(xk, wb[kk].z, acc[i][6]);
                    acc[i][7] = fmaf(xk, wb[kk].w, acc[i][7]);
                }
            }
        }
    }
#pragma unroll
    for (int i = 0; i < 8; i++) {
        int gn = nb + ngrp + 32 * i;
        if (gn < N_NODES) {
            __hip_bfloat16 hb[8];
#pragma unroll
            for (int j = 0; j < 8; j++) hb[j] = __float2bfloat16(acc[i][j]);
            *(uint4*)&H[(size_t)gn * F + f0] = *(uint4*)hb;
        }
    }
}

// per-bucket pass 1: degrees (LDS float atomics) -> dinv_g, counts -> row_off
__global__ __launch_bounds__(512) void k_deg(const long long* __restrict__ part,
                                             const int* __restrict__ base,
                                             float* __restrict__ dinv_g, int* __restrict__ row_off) {
    __shared__ float fdeg[128];
    __shared__ int   cnt[128];
    __shared__ int   sc[128];
    int b = blockIdx.x, tid = threadIdx.x;
    if (tid < 128) { fdeg[tid] = 1.0f; cnt[tid] = 0; }   // 1.0 = self-loop weight
    __syncthreads();
    int e0 = base[b], e1 = base[b + 1];
    for (int k = e0 + tid; k < e1; k += 512) {
        long long rec = part[k];
        int d7 = ((int)rec >> 17) & 127;
        atomicAdd(&fdeg[d7], __uint_as_float((unsigned)(rec >> 32)));
        atomicAdd(&cnt[d7], 1);
    }
    __syncthreads();
    int myc = 0, x = 0;
    if (tid < 128) {
        int node = b * 128 + tid;
        if (node < N_NODES) dinv_g[node] = rsqrtf(fdeg[tid]);
        myc = cnt[tid]; x = myc; sc[tid] = x;
    }
    __syncthreads();
    for (int off = 1; off < 128; off <<= 1) {
        int t = (tid < 128 && tid >= off) ? sc[tid - off] : 0;
        __syncthreads();
        if (tid < 128) { x += t; sc[tid] = x; }
        __syncthreads();
    }
    if (tid < 128) {
        int node = b * 128 + tid;
        if (node < N_NODES) row_off[node] = e0 + (x - myc);
    }
    if (b == 0 && tid == 0) row_off[N_NODES] = N_EDGES;
}

// per-bucket pass 2: scatter esec = (src*128 byte-off, w*dinv[d]*dinv[src])
__global__ __launch_bounds__(512) void k_scat(const long long* __restrict__ part,
                                              const int* __restrict__ base,
                                              const float* __restrict__ dinv_g,
                                              const int* __restrict__ row_off,
                                              int2* __restrict__ esec) {
    __shared__ int   cursor[128];
    __shared__ float sdinv[128];
    int b = blockIdx.x, tid = threadIdx.x;
    if (tid < 128) {
        int node = b * 128 + tid;
        cursor[tid] = row_off[node < N_NODES ? node : N_NODES];
        sdinv[tid]  = dinv_g[node < N_NODES ? node : 0];
    }
    __syncthreads();
    int e0 = base[b], e1 = base[b + 1];
    for (int k = e0 + tid; k < e1; k += 512) {
        long long rec = part[k];
        int lo = (int)rec;
        int d7 = (lo >> 17) & 127;
        int s  = lo & 0x1FFFF;
        float w = __uint_as_float((unsigned)(rec >> 32));
        float coef = (w * sdinv[d7]) * dinv_g[s];
        int pos = atomicAdd(&cursor[d7], 1);
        esec[pos] = make_int2(s << 7, __float_as_int(coef));   // byte off: src*128 (bf16 row)
    }
    if (b == 0 && tid < 32) esec[N_EDGES + tid] = make_int2(0, 0);  // sentinels for agg overrun
}

// ---------------- GEMM (layers 2/3): H = X_bf16[N,64] @ W[64,64], bf16 out ----------------
template <int K>
__global__ __launch_bounds__(256) void k_gemm(const unsigned short* __restrict__ X,
                                              const float* __restrict__ W,
                                              __hip_bfloat16* __restrict__ H) {
    constexpr int KC = 32;
    constexpr int XP = KC + 4;
    __shared__ float Xs[256 * XP];
    __shared__ float Ws[KC * F];
    const int tid  = threadIdx.x;
    const int fgrp = tid & 7;
    const int ngrp = tid >> 3;
    const int f0   = fgrp * 8;
    const int nb   = blockIdx.x * 256;

    float acc[8][8];
#pragma unroll
    for (int i = 0; i < 8; i++)
#pragma unroll
        for (int j = 0; j < 8; j++) acc[i][j] = 0.0f;

    for (int kc = 0; kc < K; kc += KC) {
        if (kc) __syncthreads();
#pragma unroll
        for (int pass = 0; pass < 4; pass++) {
            int idx = tid + pass * 256;
            int r = idx >> 2, q = idx & 3;
            int gr = nb + r; if (gr >= N_NODES) gr = N_NODES - 1;
            uint4 v = *(const uint4*)&X[(size_t)gr * K + kc + q * 8];
            float* dp = &Xs[r * XP + q * 8];
            dp[0] = __uint_as_float(v.x << 16);
            dp[1] = __uint_as_float(v.x & 0xffff0000u);
            dp[2] = __uint_as_float(v.y << 16);
            dp[3] = __uint_as_float(v.y & 0xffff0000u);
            dp[4] = __uint_as_float(v.z << 16);
            dp[5] = __uint_as_float(v.z & 0xffff0000u);
            dp[6] = __uint_as_float(v.w << 16);
            dp[7] = __uint_as_float(v.w & 0xffff0000u);
        }
#pragma unroll
        for (int pass = 0; pass < 2; pass++) {
            int idx = tid + pass * 256;
            float4 v = *(const float4*)&W[(size_t)(kc + (idx >> 4)) * F + (idx & 15) * 4];
            *(float4*)&Ws[idx * 4] = v;
        }
        __syncthreads();
#pragma unroll
        for (int k = 0; k < KC; k += 4) {
            float4 wa[4], wb[4];
#pragma unroll
            for (int kk = 0; kk < 4; kk++) {
                wa[kk] = *(const float4*)&Ws[(k + kk) * F + f0];
                wb[kk] = *(const float4*)&Ws[(k + kk) * F + f0 + 4];
            }
#pragma unroll
            for (int i = 0; i < 8; i++) {
                float4 xv = *(const float4*)&Xs[(ngrp + 32 * i) * XP + k];
#pragma unroll
                for (int kk = 0; kk < 4; kk++) {
                    float xk = (kk == 0) ? xv.x : (kk == 1) ? xv.y : (kk == 2) ? xv.z : xv.w;
                    acc[i][0] = fmaf(xk, wa[kk].x, acc[i][0]);
                    acc[i][1] = fmaf(xk, wa[kk].y, acc[i][1]);
                    acc[i][2] = fmaf(xk, wa[kk].z, acc[i][2]);
                    acc[i][3] = fmaf(xk, wa[kk].w, acc[i][3]);
                    acc[i][4] = fmaf(xk, wb[kk].x, acc[i][4]);
                    acc[i][5] = fmaf(xk, wb[kk].y, acc[i][5]);
                    acc[i][6] = fmaf(xk, wb[kk].z, acc[i][6]);
                    acc[i][7] = fmaf(xk, wb[kk].w, acc[i][7]);
                }
            }
        }
    }
#pragma unroll
    for (int i = 0; i < 8; i++) {
        int gn = nb + ngrp + 32 * i;
        if (gn < N_NODES) {
            __hip_bfloat16 hb[8];
#pragma unroll
            for (int j = 0; j < 8; j++) hb[j] = __float2bfloat16(acc[i][j]);
            *(uint4*)&H[(size_t)gn * F + f0] = *(uint4*)hb;
        }
    }
}

// ---------------- aggregation: O = relu(b + dinv^2*H + sum_in c*H[src]) ----------------
// FOUR nodes per wave, single 8-edge window each (round-9 proven: VGPR 44, no spill;
// the dual-window variant spilled -> 474 MB scratch writes. Keep loads interleaved
// with consumption so live ranges stay short).
__global__ __launch_bounds__(256) void k_agg(const __hip_bfloat16* __restrict__ H,
                                             const int* __restrict__ row_off,
                                             const int2* __restrict__ esec,
                                             const float* __restrict__ dinv,
                                             const float* __restrict__ bias,
                                             __hip_bfloat16* __restrict__ O) {
    int wv   = threadIdx.x >> 6;
    int lane = threadIdx.x & 63;
    int np   = blockIdx.x * 16 + wv * 4;
    int q  = lane >> 3;
    int f8 = lane & 7;
    int r0 = __builtin_amdgcn_readfirstlane(row_off[np]);
    int r1 = __builtin_amdgcn_readfirstlane(row_off[np + 1]);
    int r2 = __builtin_amdgcn_readfirstlane(row_off[np + 2]);
    int r3 = __builtin_amdgcn_readfirstlane(row_off[np + 3]);
    int r4 = __builtin_amdgcn_readfirstlane(row_off[np + 4]);
    const char* Hbase = (const char*)H;

    float a0[8], a1[8], a2[8], a3[8];
#pragma unroll
    for (int u = 0; u < 8; u++) { a0[u] = 0.0f; a1[u] = 0.0f; a2[u] = 0.0f; a3[u] = 0.0f; }

    int l0 = r1 - r0, l1 = r2 - r1, l2 = r3 - r2, l3 = r4 - r3;
    int ml = l0 > l1 ? l0 : l1;
    if (l2 > ml) ml = l2;
    if (l3 > ml) ml = l3;
    int iters = (ml + 7) >> 3;
    int j0 = r0 + q, j1 = r1 + q, j2 = r2 + q, j3 = r3 + q;
    for (int it = 0; it < iters; it++, j0 += 8, j1 += 8, j2 += 8, j3 += 8) {
        int i0 = j0 < N_EDGES ? j0 : N_EDGES;
        int i1 = j1 < N_EDGES ? j1 : N_EDGES;
        int i2 = j2 < N_EDGES ? j2 : N_EDGES;
        int i3 = j3 < N_EDGES ? j3 : N_EDGES;
        int2 ev0 = esec[i0];
        int2 ev1 = esec[i1];
        int2 ev2 = esec[i2];
        int2 ev3 = esec[i3];
        float c0 = (j0 < r1) ? __int_as_float(ev0.y) : 0.0f;
        float c1 = (j1 < r2) ? __int_as_float(ev1.y) : 0.0f;
        float c2 = (j2 < r3) ? __int_as_float(ev2.y) : 0.0f;
        float c3 = (j3 < r4) ? __int_as_float(ev3.y) : 0.0f;
        uint4 h0 = *(const uint4*)(Hbase + (unsigned)ev0.x + (f8 << 4));
        uint4 h1 = *(const uint4*)(Hbase + (unsigned)ev1.x + (f8 << 4));
        uint4 h2 = *(const uint4*)(Hbase + (unsigned)ev2.x + (f8 << 4));
        uint4 h3 = *(const uint4*)(Hbase + (unsigned)ev3.x + (f8 << 4));
        a0[0] = fmaf(c0, __uint_as_float(h0.x << 16),         a0[0]);
        a0[1] = fmaf(c0, __uint_as_float(h0.x & 0xffff0000u), a0[1]);
        a0[2] = fmaf(c0, __uint_as_float(h0.y << 16),         a0[2]);
        a0[3] = fmaf(c0, __uint_as_float(h0.y & 0xffff0000u), a0[3]);
        a0[4] = fmaf(c0, __uint_as_float(h0.z << 16),         a0[4]);
        a0[5] = fmaf(c0, __uint_as_float(h0.z & 0xffff0000u), a0[5]);
        a0[6] = fmaf(c0, __uint_as_float(h0.w << 16),         a0[6]);
        a0[7] = fmaf(c0, __uint_as_float(h0.w & 0xffff0000u), a0[7]);
        a1[0] = fmaf(c1, __uint_as_float(h1.x << 16),         a1[0]);
        a1[1] = fmaf(c1, __uint_as_float(h1.x & 0xffff0000u), a1[1]);
        a1[2] = fmaf(c1, __uint_as_float(h1.y << 16),         a1[2]);
        a1[3] = fmaf(c1, __uint_as_float(h1.y & 0xffff0000u), a1[3]);
        a1[4] = fmaf(c1, __uint_as_float(h1.z << 16),         a1[4]);
        a1[5] = fmaf(c1, __uint_as_float(h1.z & 0xffff0000u), a1[5]);
        a1[6] = fmaf(c1, __uint_as_float(h1.w << 16),         a1[6]);
        a1[7] = fmaf(c1, __uint_as_float(h1.w & 0xffff0000u), a1[7]);
        a2[0] = fmaf(c2, __uint_as_float(h2.x << 16),         a2[0]);
        a2[1] = fmaf(c2, __uint_as_float(h2.x & 0xffff0000u), a2[1]);
        a2[2] = fmaf(c2, __uint_as_float(h2.y << 16),         a2[2]);
        a2[3] = fmaf(c2, __uint_as_float(h2.y & 0xffff0000u), a2[3]);
        a2[4] = fmaf(c2, __uint_as_float(h2.z << 16),         a2[4]);
        a2[5] = fmaf(c2, __uint_as_float(h2.z & 0xffff0000u), a2[5]);
        a2[6] = fmaf(c2, __uint_as_float(h2.w << 16),         a2[6]);
        a2[7] = fmaf(c2, __uint_as_float(h2.w & 0xffff0000u), a2[7]);
        a3[0] = fmaf(c3, __uint_as_float(h3.x << 16),         a3[0]);
        a3[1] = fmaf(c3, __uint_as_float(h3.x & 0xffff0000u), a3[1]);
        a3[2] = fmaf(c3, __uint_as_float(h3.y << 16),         a3[2]);
        a3[3] = fmaf(c3, __uint_as_float(h3.y & 0xffff0000u), a3[3]);
        a3[4] = fmaf(c3, __uint_as_float(h3.z << 16),         a3[4]);
        a3[5] = fmaf(c3, __uint_as_float(h3.z & 0xffff0000u), a3[5]);
        a3[6] = fmaf(c3, __uint_as_float(h3.w << 16),         a3[6]);
        a3[7] = fmaf(c3, __uint_as_float(h3.w & 0xffff0000u), a3[7]);
    }
#pragma unroll
    for (int m = 8; m < 64; m <<= 1) {
#pragma unroll
        for (int u = 0; u < 8; u++) {
            a0[u] += __shfl_xor(a0[u], m);
            a1[u] += __shfl_xor(a1[u], m);
            a2[u] += __shfl_xor(a2[u], m);
            a3[u] += __shfl_xor(a3[u], m);
        }
    }
    if (q < 4) {
        int node = np + q;
        float av[8];
#pragma unroll
        for (int u = 0; u < 8; u++) {
            float t01 = (q & 1) ? a1[u] : a0[u];
            float t23 = (q & 1) ? a3[u] : a2[u];
            av[u] = (q & 2) ? t23 : t01;
        }
        float di = dinv[node];
        float di2 = di * di;
        uint4 hs = *(const uint4*)(Hbase + (size_t)node * 128 + (f8 << 4));
        float hv[8];
        hv[0] = __uint_as_float(hs.x << 16);
        hv[1] = __uint_as_float(hs.x & 0xffff0000u);
        hv[2] = __uint_as_float(hs.y << 16);
        hv[3] = __uint_as_float(hs.y & 0xffff0000u);
        hv[4] = __uint_as_float(hs.z << 16);
        hv[5] = __uint_as_float(hs.z & 0xffff0000u);
        hv[6] = __uint_as_float(hs.w << 16);
        hv[7] = __uint_as_float(hs.w & 0xffff0000u);
        const float4* bp = (const float4*)(bias + f8 * 8);
        float4 bv0 = bp[0], bv1 = bp[1];
        float r[8];
        r[0] = fmaxf(av[0] + bv0.x + di2 * hv[0], 0.0f);
        r[1] = fmaxf(av[1] + bv0.y + di2 * hv[1], 0.0f);
        r[2] = fmaxf(av[2] + bv0.z + di2 * hv[2], 0.0f);
        r[3] = fmaxf(av[3] + bv0.w + di2 * hv[3], 0.0f);
        r[4] = fmaxf(av[4] + bv1.x + di2 * hv[4], 0.0f);
        r[5] = fmaxf(av[5] + bv1.y + di2 * hv[5], 0.0f);
        r[6] = fmaxf(av[6] + bv1.z + di2 * hv[6], 0.0f);
        r[7] = fmaxf(av[7] + bv1.w + di2 * hv[7], 0.0f);
        __hip_bfloat16 hb[8];
#pragma unroll
        for (int u = 0; u < 8; u++) hb[u] = __float2bfloat16(r[u]);
        *(uint4*)&O[(size_t)node * F + f8 * 8] = *(uint4*)hb;
    }
}

// ---------------- fused mean-pool + final linear (bf16 input) ----------------
__global__ __launch_bounds__(256) void k_pool_linear(const __hip_bfloat16* __restrict__ H,
                                                     const int* __restrict__ gstart,
                                                     const float* __restrict__ Wl,
                                                     const float* __restrict__ bl,
                                                     float* __restrict__ out) {
    int g = blockIdx.x;
    int beg = gstart[g], end = gstart[g + 1];
    int lane = threadIdx.x & 63, wv = threadIdx.x >> 6;
    float acc = 0.0f;
    for (int r = beg + wv; r < end; r += 4)
        acc += __bfloat162float(H[(size_t)r * F + lane]);
    __shared__ float s[4][F];
    s[wv][lane] = acc;
    __syncthreads();
    if (wv == 0) {
        float tot = s[0][lane] + s[1][lane] + s[2][lane] + s[3][lane];
        float cntf = (float)(end - beg);
        float p = tot / fmaxf(cntf, 1.0f);
        for (int c = 0; c < 10; c++) {
            float v = p * Wl[lane * 10 + c];
            for (int off = 32; off; off >>= 1) v += __shfl_down(v, off);
            if (lane == 0) out[g * 10 + c] = v + bl[c];
        }
    }
}

// ---------------- launch ----------------

extern "C" void kernel_launch(void* const* d_in, const int* in_sizes, int n_in,
                              void* d_out, int out_size, void* d_ws, size_t ws_size,
                              hipStream_t stream) {
    const float* x    = (const float*)d_in[0];
    const int*   ei   = (const int*)d_in[1];
    const float* ea   = (const float*)d_in[2];
    const int*   bat  = (const int*)d_in[3];
    const float* W1   = (const float*)d_in[4];
    const float* b1   = (const float*)d_in[5];
    const float* W2   = (const float*)d_in[6];
    const float* b2   = (const float*)d_in[7];
    const float* W3   = (const float*)d_in[8];
    const float* b3   = (const float*)d_in[9];
    const float* Wl   = (const float*)d_in[10];
    const float* bl   = (const float*)d_in[11];
    float* out = (float*)d_out;

    const int* src = ei;
    const int* dst = ei + N_EDGES;

    char* ws = (char*)d_ws;
    size_t off = 0;
    auto carve = [&](size_t bytes) {
        void* p = ws + off;
        off += (bytes + 255) & ~(size_t)255;
        return p;
    };
    // part must not alias hbuf: GEMM1 writes hbuf concurrently with the
    // partition scatter inside the fused dispatch
    float*          dinv    = (float*)carve(N_NODES * 4);
    int*            row_off = (int*)  carve((N_NODES + 1) * 4);
    int2*           esec    = (int2*) carve(((size_t)N_EDGES + 32) * 8);        // 12.8 MB
    __hip_bfloat16* hbuf    = (__hip_bfloat16*)carve((size_t)N_NODES * F * 2);  // 12.8 MB
    __hip_bfloat16* obuf    = (__hip_bfloat16*)carve((size_t)N_NODES * F * 2);  // 12.8 MB
    long long*      part    = (long long*)carve((size_t)N_EDGES * 8);           // 12.8 MB
    int*            hist    = (int*)  carve((size_t)NCHUNK * NBUCK * 4);        // 1.22 MB
    int*            btot    = (int*)  carve((NBUCK + 8) * 4);
    int*            base    = (int*)  carve((NBUCK + 8) * 4);
    int*            gstart  = (int*)  carve((N_GRAPHS + 1) * 4);
    (void)ws_size; (void)in_sizes; (void)n_in; (void)out_size;

    k_hist        <<<NCHUNK,      1024, 0, stream>>>(dst, hist);
    k_colscan     <<<NBUCK,       512,  0, stream>>>(hist, btot);
    k_bscan_gstart<<<2,           512,  0, stream>>>(btot, base, bat, gstart);
    k_part_gemm1  <<<NCHUNK + GB, 256,  0, stream>>>(src, dst, ea, hist, base, part,
                                                     x, W1, hbuf);
    k_deg         <<<NBUCK,       512,  0, stream>>>(part, base, dinv, row_off);
    k_scat        <<<NBUCK,       512,  0, stream>>>(part, base, dinv, row_off, esec);

    k_agg<<<N_NODES / 16, 256, 0, stream>>>(hbuf, row_off, esec, dinv, b1, obuf);
    k_gemm<64><<<GB, 256, 0, stream>>>((const unsigned short*)obuf, W2, hbuf);
    k_agg<<<N_NODES / 16, 256, 0, stream>>>(hbuf, row_off, esec, dinv, b2, obuf);
    k_gemm<64><<<GB, 256, 0, stream>>>((const unsigned short*)obuf, W3, hbuf);
    k_agg<<<N_NODES / 16, 256, 0, stream>>>(hbuf, row_off, esec, dinv, b3, obuf);

    k_pool_linear<<<N_GRAPHS, 256, 0, stream>>>(obuf, gstart, Wl, bl, out);
}

// Round 12
// 373.575 us; speedup vs baseline: 1.6043x; 1.0178x over previous
//
#include <hip/hip_runtime.h>
#include <hip/hip_bf16.h>

#define N_NODES  100000
#define N_EDGES  1600000
#define N_GRAPHS 256
#define F 64
#define NBUCK  782    // ceil(N_NODES/128), bucket = dst >> 7
#define CHUNK  4096   // edges per partition chunk
#define NCHUNK 391    // ceil(1.6M/4096)
#define GB     391    // ceil(N_NODES/256) gemm blocks (256 nodes/block)

// ======== atomic-free CSR build: two-level counting sort ========

__global__ __launch_bounds__(1024) void k_hist(const int* __restrict__ dst, int* __restrict__ hist) {
    __shared__ int lh[NBUCK];
    int tid = threadIdx.x, chunk = blockIdx.x;
    for (int j = tid; j < NBUCK; j += 1024) lh[j] = 0;
    __syncthreads();
    int e0 = chunk * CHUNK;
#pragma unroll
    for (int i = 0; i < CHUNK / 1024; i++) {
        int e = e0 + i * 1024 + tid;
        if (e < N_EDGES) atomicAdd(&lh[dst[e] >> 7], 1);
    }
    __syncthreads();
    for (int j = tid; j < NBUCK; j += 1024) hist[chunk * NBUCK + j] = lh[j];
}

__global__ __launch_bounds__(512) void k_colscan(int* __restrict__ hist, int* __restrict__ btot) {
    __shared__ int ts[512];
    int b = blockIdx.x, tid = threadIdx.x;
    int v = (tid < NCHUNK) ? hist[tid * NBUCK + b] : 0;
    ts[tid] = v;
    __syncthreads();
    int x = v;
    for (int off = 1; off < 512; off <<= 1) {
        int t = (tid >= off) ? ts[tid - off] : 0;
        __syncthreads();
        x += t; ts[tid] = x;
        __syncthreads();
    }
    if (tid < NCHUNK) hist[tid * NBUCK + b] = x - v;
    if (tid == 511) btot[b] = x;
}

// block 0: scan bucket totals -> base; block 1: graph-boundary binary search
__global__ __launch_bounds__(512) void k_bscan_gstart(const int* __restrict__ btot, int* __restrict__ base,
                                                      const int* __restrict__ batch, int* __restrict__ gstart) {
    if (blockIdx.x == 1) {
        int g = threadIdx.x;
        if (g > N_GRAPHS) return;
        int lo = 0, hi = N_NODES;
        while (lo < hi) {
            int mid = (lo + hi) >> 1;
            if (batch[mid] < g) lo = mid + 1; else hi = mid;
        }
        gstart[g] = lo;
        return;
    }
    __shared__ int ts[256];
    int tid = threadIdx.x;
    int v[4], loc[4], run = 0;
    if (tid < 256) {
#pragma unroll
        for (int k = 0; k < 4; k++) {
            int c = tid * 4 + k;
            v[k] = (c < NBUCK) ? btot[c] : 0;
            loc[k] = run; run += v[k];
        }
        ts[tid] = run;
    }
    __syncthreads();
    int x = run;
    for (int off = 1; off < 256; off <<= 1) {
        int t = (tid >= off && tid < 256) ? ts[tid - off] : 0;
        __syncthreads();
        if (tid < 256) { x += t; ts[tid] = x; }
        __syncthreads();
    }
    if (tid < 256) {
        int texcl = x - run;
#pragma unroll
        for (int k = 0; k < 4; k++) {
            int c = tid * 4 + k;
            if (c < NBUCK) base[c] = texcl + loc[k];
        }
        if (tid == 255) base[NBUCK] = x;
    }
}

// edge partition (1024 threads, 3.1 KB LDS -> high occupancy; r8/r9 proven)
__global__ __launch_bounds__(1024) void k_partition(const int* __restrict__ src, const int* __restrict__ dst,
                                                    const float* __restrict__ ew,
                                                    const int* __restrict__ hist, const int* __restrict__ base,
                                                    long long* __restrict__ part) {
    __shared__ int cursor[NBUCK];
    int tid = threadIdx.x, chunk = blockIdx.x;
    for (int j = tid; j < NBUCK; j += 1024) cursor[j] = base[j] + hist[chunk * NBUCK + j];
    __syncthreads();
    int e0 = chunk * CHUNK;
#pragma unroll
    for (int i = 0; i < CHUNK / 1024; i++) {
        int e = e0 + i * 1024 + tid;
        if (e < N_EDGES) {
            int d = dst[e];
            int pos = atomicAdd(&cursor[d >> 7], 1);
            unsigned lo = (unsigned)src[e] | ((unsigned)(d & 127) << 17);
            long long rec = (long long)((unsigned long long)lo |
                            ((unsigned long long)__float_as_uint(ew[e]) << 32));
            part[pos] = rec;
        }
    }
}

// per-bucket pass 1: degrees (LDS float atomics) -> dinv_g, counts -> row_off
__global__ __launch_bounds__(512) void k_deg(const long long* __restrict__ part,
                                             const int* __restrict__ base,
                                             float* __restrict__ dinv_g, int* __restrict__ row_off) {
    __shared__ float fdeg[128];
    __shared__ int   cnt[128];
    __shared__ int   sc[128];
    int b = blockIdx.x, tid = threadIdx.x;
    if (tid < 128) { fdeg[tid] = 1.0f; cnt[tid] = 0; }   // 1.0 = self-loop weight
    __syncthreads();
    int e0 = base[b], e1 = base[b + 1];
    for (int k = e0 + tid; k < e1; k += 512) {
        long long rec = part[k];
        int d7 = ((int)rec >> 17) & 127;
        atomicAdd(&fdeg[d7], __uint_as_float((unsigned)(rec >> 32)));
        atomicAdd(&cnt[d7], 1);
    }
    __syncthreads();
    int myc = 0, x = 0;
    if (tid < 128) {
        int node = b * 128 + tid;
        if (node < N_NODES) dinv_g[node] = rsqrtf(fdeg[tid]);
        myc = cnt[tid]; x = myc; sc[tid] = x;
    }
    __syncthreads();
    for (int off = 1; off < 128; off <<= 1) {
        int t = (tid < 128 && tid >= off) ? sc[tid - off] : 0;
        __syncthreads();
        if (tid < 128) { x += t; sc[tid] = x; }
        __syncthreads();
    }
    if (tid < 128) {
        int node = b * 128 + tid;
        if (node < N_NODES) row_off[node] = e0 + (x - myc);
    }
    if (b == 0 && tid == 0) row_off[N_NODES] = N_EDGES;
}

// per-bucket pass 2: scatter esec = (src*128 byte-off, w*dinv[d]*dinv[src])
__global__ __launch_bounds__(512) void k_scat(const long long* __restrict__ part,
                                              const int* __restrict__ base,
                                              const float* __restrict__ dinv_g,
                                              const int* __restrict__ row_off,
                                              int2* __restrict__ esec) {
    __shared__ int   cursor[128];
    __shared__ float sdinv[128];
    int b = blockIdx.x, tid = threadIdx.x;
    if (tid < 128) {
        int node = b * 128 + tid;
        cursor[tid] = row_off[node < N_NODES ? node : N_NODES];
        sdinv[tid]  = dinv_g[node < N_NODES ? node : 0];
    }
    __syncthreads();
    int e0 = base[b], e1 = base[b + 1];
    for (int k = e0 + tid; k < e1; k += 512) {
        long long rec = part[k];
        int lo = (int)rec;
        int d7 = (lo >> 17) & 127;
        int s  = lo & 0x1FFFF;
        float w = __uint_as_float((unsigned)(rec >> 32));
        float coef = (w * sdinv[d7]) * dinv_g[s];
        int pos = atomicAdd(&cursor[d7], 1);
        esec[pos] = make_int2(s << 7, __float_as_int(coef));   // byte off: src*128 (bf16 row)
    }
    if (b == 0 && tid < 32) esec[N_EDGES + tid] = make_int2(0, 0);  // sentinels for agg overrun
}

// ---------------- GEMM1: H = X_f32[N,128] @ W[128,64], bf16 out ----------------
__global__ __launch_bounds__(256) void k_gemm1(const float* __restrict__ X,
                                               const float* __restrict__ W,
                                               __hip_bfloat16* __restrict__ H) {
    constexpr int K = 128;
    constexpr int KC = 32;
    constexpr int XP = KC + 4;
    __shared__ float Xs[256 * XP];
    __shared__ float Ws[KC * F];
    const int tid  = threadIdx.x;
    const int fgrp = tid & 7;
    const int ngrp = tid >> 3;
    const int f0   = fgrp * 8;
    const int nb   = blockIdx.x * 256;

    float acc[8][8];
#pragma unroll
    for (int i = 0; i < 8; i++)
#pragma unroll
        for (int j = 0; j < 8; j++) acc[i][j] = 0.0f;

    for (int kc = 0; kc < K; kc += KC) {
        if (kc) __syncthreads();
#pragma unroll
        for (int pass = 0; pass < 8; pass++) {
            int idx = tid + pass * 256;
            int r = idx >> 3, q = idx & 7;
            int gr = nb + r; if (gr >= N_NODES) gr = N_NODES - 1;
            float4 v = *(const float4*)&X[(size_t)gr * K + kc + q * 4];
            *(float4*)&Xs[r * XP + q * 4] = v;
        }
#pragma unroll
        for (int pass = 0; pass < 2; pass++) {
            int idx = tid + pass * 256;
            float4 v = *(const float4*)&W[(size_t)(kc + (idx >> 4)) * F + (idx & 15) * 4];
            *(float4*)&Ws[idx * 4] = v;
        }
        __syncthreads();
#pragma unroll
        for (int k = 0; k < KC; k += 4) {
            float4 wa[4], wb[4];
#pragma unroll
            for (int kk = 0; kk < 4; kk++) {
                wa[kk] = *(const float4*)&Ws[(k + kk) * F + f0];
                wb[kk] = *(const float4*)&Ws[(k + kk) * F + f0 + 4];
            }
#pragma unroll
            for (int i = 0; i < 8; i++) {
                float4 xv = *(const float4*)&Xs[(ngrp + 32 * i) * XP + k];
#pragma unroll
                for (int kk = 0; kk < 4; kk++) {
                    float xk = (kk == 0) ? xv.x : (kk == 1) ? xv.y : (kk == 2) ? xv.z : xv.w;
                    acc[i][0] = fmaf(xk, wa[kk].x, acc[i][0]);
                    acc[i][1] = fmaf(xk, wa[kk].y, acc[i][1]);
                    acc[i][2] = fmaf(xk, wa[kk].z, acc[i][2]);
                    acc[i][3] = fmaf(xk, wa[kk].w, acc[i][3]);
                    acc[i][4] = fmaf(xk, wb[kk].x, acc[i][4]);
                    acc[i][5] = fmaf(xk, wb[kk].y, acc[i][5]);
                    acc[i][6] = fmaf(xk, wb[kk].z, acc[i][6]);
                    acc[i][7] = fmaf(xk, wb[kk].w, acc[i][7]);
                }
            }
        }
    }
#pragma unroll
    for (int i = 0; i < 8; i++) {
        int gn = nb + ngrp + 32 * i;
        if (gn < N_NODES) {
            __hip_bfloat16 hb[8];
#pragma unroll
            for (int j = 0; j < 8; j++) hb[j] = __float2bfloat16(acc[i][j]);
            *(uint4*)&H[(size_t)gn * F + f0] = *(uint4*)hb;
        }
    }
}

// ---------------- GEMM (layers 2/3): H = X_bf16[N,64] @ W[64,64], bf16 out ----------------
template <int K>
__global__ __launch_bounds__(256) void k_gemm(const unsigned short* __restrict__ X,
                                              const float* __restrict__ W,
                                              __hip_bfloat16* __restrict__ H) {
    constexpr int KC = 32;
    constexpr int XP = KC + 4;
    __shared__ float Xs[256 * XP];
    __shared__ float Ws[KC * F];
    const int tid  = threadIdx.x;
    const int fgrp = tid & 7;
    const int ngrp = tid >> 3;
    const int f0   = fgrp * 8;
    const int nb   = blockIdx.x * 256;

    float acc[8][8];
#pragma unroll
    for (int i = 0; i < 8; i++)
#pragma unroll
        for (int j = 0; j < 8; j++) acc[i][j] = 0.0f;

    for (int kc = 0; kc < K; kc += KC) {
        if (kc) __syncthreads();
#pragma unroll
        for (int pass = 0; pass < 4; pass++) {
            int idx = tid + pass * 256;
            int r = idx >> 2, q = idx & 3;
            int gr = nb + r; if (gr >= N_NODES) gr = N_NODES - 1;
            uint4 v = *(const uint4*)&X[(size_t)gr * K + kc + q * 8];
            float* dp = &Xs[r * XP + q * 8];
            dp[0] = __uint_as_float(v.x << 16);
            dp[1] = __uint_as_float(v.x & 0xffff0000u);
            dp[2] = __uint_as_float(v.y << 16);
            dp[3] = __uint_as_float(v.y & 0xffff0000u);
            dp[4] = __uint_as_float(v.z << 16);
            dp[5] = __uint_as_float(v.z & 0xffff0000u);
            dp[6] = __uint_as_float(v.w << 16);
            dp[7] = __uint_as_float(v.w & 0xffff0000u);
        }
#pragma unroll
        for (int pass = 0; pass < 2; pass++) {
            int idx = tid + pass * 256;
            float4 v = *(const float4*)&W[(size_t)(kc + (idx >> 4)) * F + (idx & 15) * 4];
            *(float4*)&Ws[idx * 4] = v;
        }
        __syncthreads();
#pragma unroll
        for (int k = 0; k < KC; k += 4) {
            float4 wa[4], wb[4];
#pragma unroll
            for (int kk = 0; kk < 4; kk++) {
                wa[kk] = *(const float4*)&Ws[(k + kk) * F + f0];
                wb[kk] = *(const float4*)&Ws[(k + kk) * F + f0 + 4];
            }
#pragma unroll
            for (int i = 0; i < 8; i++) {
                float4 xv = *(const float4*)&Xs[(ngrp + 32 * i) * XP + k];
#pragma unroll
                for (int kk = 0; kk < 4; kk++) {
                    float xk = (kk == 0) ? xv.x : (kk == 1) ? xv.y : (kk == 2) ? xv.z : xv.w;
                    acc[i][0] = fmaf(xk, wa[kk].x, acc[i][0]);
                    acc[i][1] = fmaf(xk, wa[kk].y, acc[i][1]);
                    acc[i][2] = fmaf(xk, wa[kk].z, acc[i][2]);
                    acc[i][3] = fmaf(xk, wa[kk].w, acc[i][3]);
                    acc[i][4] = fmaf(xk, wb[kk].x, acc[i][4]);
                    acc[i][5] = fmaf(xk, wb[kk].y, acc[i][5]);
                    acc[i][6] = fmaf(xk, wb[kk].z, acc[i][6]);
                    acc[i][7] = fmaf(xk, wb[kk].w, acc[i][7]);
                }
            }
        }
    }
#pragma unroll
    for (int i = 0; i < 8; i++) {
        int gn = nb + ngrp + 32 * i;
        if (gn < N_NODES) {
            __hip_bfloat16 hb[8];
#pragma unroll
            for (int j = 0; j < 8; j++) hb[j] = __float2bfloat16(acc[i][j]);
            *(uint4*)&H[(size_t)gn * F + f0] = *(uint4*)hb;
        }
    }
}

// ---------------- aggregation: O = relu(b + dinv^2*H + sum_in c*H[src]) ----------------
// FOUR nodes per wave, software-pipelined esec: next window's 4 esec entries are
// prefetched while the current window's gathers are in flight, overlapping the
// two dependent latencies. h-values are consumed immediately (short live ranges);
// only ev_next (8 VGPRs) is added pressure — no spill (r10 lesson).
__global__ __launch_bounds__(256) void k_agg(const __hip_bfloat16* __restrict__ H,
                                             const int* __restrict__ row_off,
                                             const int2* __restrict__ esec,
                                             const float* __restrict__ dinv,
                                             const float* __restrict__ bias,
                                             __hip_bfloat16* __restrict__ O) {
    int wv   = threadIdx.x >> 6;
    int lane = threadIdx.x & 63;
    int np   = blockIdx.x * 16 + wv * 4;
    int q  = lane >> 3;
    int f8 = lane & 7;
    int r0 = __builtin_amdgcn_readfirstlane(row_off[np]);
    int r1 = __builtin_amdgcn_readfirstlane(row_off[np + 1]);
    int r2 = __builtin_amdgcn_readfirstlane(row_off[np + 2]);
    int r3 = __builtin_amdgcn_readfirstlane(row_off[np + 3]);
    int r4 = __builtin_amdgcn_readfirstlane(row_off[np + 4]);
    const char* Hbase = (const char*)H;

    float a0[8], a1[8], a2[8], a3[8];
#pragma unroll
    for (int u = 0; u < 8; u++) { a0[u] = 0.0f; a1[u] = 0.0f; a2[u] = 0.0f; a3[u] = 0.0f; }

    int l0 = r1 - r0, l1 = r2 - r1, l2 = r3 - r2, l3 = r4 - r3;
    int ml = l0 > l1 ? l0 : l1;
    if (l2 > ml) ml = l2;
    if (l3 > ml) ml = l3;
    int iters = (ml + 7) >> 3;
    int j0 = r0 + q, j1 = r1 + q, j2 = r2 + q, j3 = r3 + q;

    // prologue: prefetch window 0's esec
    int2 ev0 = esec[j0 < N_EDGES ? j0 : N_EDGES];
    int2 ev1 = esec[j1 < N_EDGES ? j1 : N_EDGES];
    int2 ev2 = esec[j2 < N_EDGES ? j2 : N_EDGES];
    int2 ev3 = esec[j3 < N_EDGES ? j3 : N_EDGES];

    for (int it = 0; it < iters; it++) {
        int n0 = j0 + 8, n1 = j1 + 8, n2 = j2 + 8, n3 = j3 + 8;
        int2 en0 = esec[n0 < N_EDGES ? n0 : N_EDGES];   // prefetch next window
        int2 en1 = esec[n1 < N_EDGES ? n1 : N_EDGES];
        int2 en2 = esec[n2 < N_EDGES ? n2 : N_EDGES];
        int2 en3 = esec[n3 < N_EDGES ? n3 : N_EDGES];

        float c0 = (j0 < r1) ? __int_as_float(ev0.y) : 0.0f;
        float c1 = (j1 < r2) ? __int_as_float(ev1.y) : 0.0f;
        float c2 = (j2 < r3) ? __int_as_float(ev2.y) : 0.0f;
        float c3 = (j3 < r4) ? __int_as_float(ev3.y) : 0.0f;
        uint4 h0 = *(const uint4*)(Hbase + (unsigned)ev0.x + (f8 << 4));
        uint4 h1 = *(const uint4*)(Hbase + (unsigned)ev1.x + (f8 << 4));
        uint4 h2 = *(const uint4*)(Hbase + (unsigned)ev2.x + (f8 << 4));
        uint4 h3 = *(const uint4*)(Hbase + (unsigned)ev3.x + (f8 << 4));
        a0[0] = fmaf(c0, __uint_as_float(h0.x << 16),         a0[0]);
        a0[1] = fmaf(c0, __uint_as_float(h0.x & 0xffff0000u), a0[1]);
        a0[2] = fmaf(c0, __uint_as_float(h0.y << 16),         a0[2]);
        a0[3] = fmaf(c0, __uint_as_float(h0.y & 0xffff0000u), a0[3]);
        a0[4] = fmaf(c0, __uint_as_float(h0.z << 16),         a0[4]);
        a0[5] = fmaf(c0, __uint_as_float(h0.z & 0xffff0000u), a0[5]);
        a0[6] = fmaf(c0, __uint_as_float(h0.w << 16),         a0[6]);
        a0[7] = fmaf(c0, __uint_as_float(h0.w & 0xffff0000u), a0[7]);
        a1[0] = fmaf(c1, __uint_as_float(h1.x << 16),         a1[0]);
        a1[1] = fmaf(c1, __uint_as_float(h1.x & 0xffff0000u), a1[1]);
        a1[2] = fmaf(c1, __uint_as_float(h1.y << 16),         a1[2]);
        a1[3] = fmaf(c1, __uint_as_float(h1.y & 0xffff0000u), a1[3]);
        a1[4] = fmaf(c1, __uint_as_float(h1.z << 16),         a1[4]);
        a1[5] = fmaf(c1, __uint_as_float(h1.z & 0xffff0000u), a1[5]);
        a1[6] = fmaf(c1, __uint_as_float(h1.w << 16),         a1[6]);
        a1[7] = fmaf(c1, __uint_as_float(h1.w & 0xffff0000u), a1[7]);
        a2[0] = fmaf(c2, __uint_as_float(h2.x << 16),         a2[0]);
        a2[1] = fmaf(c2, __uint_as_float(h2.x & 0xffff0000u), a2[1]);
        a2[2] = fmaf(c2, __uint_as_float(h2.y << 16),         a2[2]);
        a2[3] = fmaf(c2, __uint_as_float(h2.y & 0xffff0000u), a2[3]);
        a2[4] = fmaf(c2, __uint_as_float(h2.z << 16),         a2[4]);
        a2[5] = fmaf(c2, __uint_as_float(h2.z & 0xffff0000u), a2[5]);
        a2[6] = fmaf(c2, __uint_as_float(h2.w << 16),         a2[6]);
        a2[7] = fmaf(c2, __uint_as_float(h2.w & 0xffff0000u), a2[7]);
        a3[0] = fmaf(c3, __uint_as_float(h3.x << 16),         a3[0]);
        a3[1] = fmaf(c3, __uint_as_float(h3.x & 0xffff0000u), a3[1]);
        a3[2] = fmaf(c3, __uint_as_float(h3.y << 16),         a3[2]);
        a3[3] = fmaf(c3, __uint_as_float(h3.y & 0xffff0000u), a3[3]);
        a3[4] = fmaf(c3, __uint_as_float(h3.z << 16),         a3[4]);
        a3[5] = fmaf(c3, __uint_as_float(h3.z & 0xffff0000u), a3[5]);
        a3[6] = fmaf(c3, __uint_as_float(h3.w << 16),         a3[6]);
        a3[7] = fmaf(c3, __uint_as_float(h3.w & 0xffff0000u), a3[7]);

        ev0 = en0; ev1 = en1; ev2 = en2; ev3 = en3;
        j0 = n0; j1 = n1; j2 = n2; j3 = n3;
    }
#pragma unroll
    for (int m = 8; m < 64; m <<= 1) {
#pragma unroll
        for (int u = 0; u < 8; u++) {
            a0[u] += __shfl_xor(a0[u], m);
            a1[u] += __shfl_xor(a1[u], m);
            a2[u] += __shfl_xor(a2[u], m);
            a3[u] += __shfl_xor(a3[u], m);
        }
    }
    if (q < 4) {
        int node = np + q;
        float av[8];
#pragma unroll
        for (int u = 0; u < 8; u++) {
            float t01 = (q & 1) ? a1[u] : a0[u];
            float t23 = (q & 1) ? a3[u] : a2[u];
            av[u] = (q & 2) ? t23 : t01;
        }
        float di = dinv[node];
        float di2 = di * di;
        uint4 hs = *(const uint4*)(Hbase + (size_t)node * 128 + (f8 << 4));
        float hv[8];
        hv[0] = __uint_as_float(hs.x << 16);
        hv[1] = __uint_as_float(hs.x & 0xffff0000u);
        hv[2] = __uint_as_float(hs.y << 16);
        hv[3] = __uint_as_float(hs.y & 0xffff0000u);
        hv[4] = __uint_as_float(hs.z << 16);
        hv[5] = __uint_as_float(hs.z & 0xffff0000u);
        hv[6] = __uint_as_float(hs.w << 16);
        hv[7] = __uint_as_float(hs.w & 0xffff0000u);
        const float4* bp = (const float4*)(bias + f8 * 8);
        float4 bv0 = bp[0], bv1 = bp[1];
        float r[8];
        r[0] = fmaxf(av[0] + bv0.x + di2 * hv[0], 0.0f);
        r[1] = fmaxf(av[1] + bv0.y + di2 * hv[1], 0.0f);
        r[2] = fmaxf(av[2] + bv0.z + di2 * hv[2], 0.0f);
        r[3] = fmaxf(av[3] + bv0.w + di2 * hv[3], 0.0f);
        r[4] = fmaxf(av[4] + bv1.x + di2 * hv[4], 0.0f);
        r[5] = fmaxf(av[5] + bv1.y + di2 * hv[5], 0.0f);
        r[6] = fmaxf(av[6] + bv1.z + di2 * hv[6], 0.0f);
        r[7] = fmaxf(av[7] + bv1.w + di2 * hv[7], 0.0f);
        __hip_bfloat16 hb[8];
#pragma unroll
        for (int u = 0; u < 8; u++) hb[u] = __float2bfloat16(r[u]);
        *(uint4*)&O[(size_t)node * F + f8 * 8] = *(uint4*)hb;
    }
}

// ---------------- fused mean-pool + final linear (bf16 input) ----------------
__global__ __launch_bounds__(256) void k_pool_linear(const __hip_bfloat16* __restrict__ H,
                                                     const int* __restrict__ gstart,
                                                     const float* __restrict__ Wl,
                                                     const float* __restrict__ bl,
                                                     float* __restrict__ out) {
    int g = blockIdx.x;
    int beg = gstart[g], end = gstart[g + 1];
    int lane = threadIdx.x & 63, wv = threadIdx.x >> 6;
    float acc = 0.0f;
    for (int r = beg + wv; r < end; r += 4)
        acc += __bfloat162float(H[(size_t)r * F + lane]);
    __shared__ float s[4][F];
    s[wv][lane] = acc;
    __syncthreads();
    if (wv == 0) {
        float tot = s[0][lane] + s[1][lane] + s[2][lane] + s[3][lane];
        float cntf = (float)(end - beg);
        float p = tot / fmaxf(cntf, 1.0f);
        for (int c = 0; c < 10; c++) {
            float v = p * Wl[lane * 10 + c];
            for (int off = 32; off; off >>= 1) v += __shfl_down(v, off);
            if (lane == 0) out[g * 10 + c] = v + bl[c];
        }
    }
}

// ---------------- launch ----------------

extern "C" void kernel_launch(void* const* d_in, const int* in_sizes, int n_in,
                              void* d_out, int out_size, void* d_ws, size_t ws_size,
                              hipStream_t stream) {
    const float* x    = (const float*)d_in[0];
    const int*   ei   = (const int*)d_in[1];
    const float* ea   = (const float*)d_in[2];
    const int*   bat  = (const int*)d_in[3];
    const float* W1   = (const float*)d_in[4];
    const float* b1   = (const float*)d_in[5];
    const float* W2   = (const float*)d_in[6];
    const float* b2   = (const float*)d_in[7];
    const float* W3   = (const float*)d_in[8];
    const float* b3   = (const float*)d_in[9];
    const float* Wl   = (const float*)d_in[10];
    const float* bl   = (const float*)d_in[11];
    float* out = (float*)d_out;

    const int* src = ei;
    const int* dst = ei + N_EDGES;

    char* ws = (char*)d_ws;
    size_t off = 0;
    auto carve = [&](size_t bytes) {
        void* p = ws + off;
        off += (bytes + 255) & ~(size_t)255;
        return p;
    };
    float*          dinv    = (float*)carve(N_NODES * 4);
    int*            row_off = (int*)  carve((N_NODES + 1) * 4);
    int2*           esec    = (int2*) carve(((size_t)N_EDGES + 32) * 8);        // 12.8 MB
    __hip_bfloat16* hbuf    = (__hip_bfloat16*)carve((size_t)N_NODES * F * 2);  // 12.8 MB
    __hip_bfloat16* obuf    = (__hip_bfloat16*)carve((size_t)N_NODES * F * 2);  // 12.8 MB
    long long*      part    = (long long*)carve((size_t)N_EDGES * 8);           // 12.8 MB
    int*            hist    = (int*)  carve((size_t)NCHUNK * NBUCK * 4);        // 1.22 MB
    int*            btot    = (int*)  carve((NBUCK + 8) * 4);
    int*            base    = (int*)  carve((NBUCK + 8) * 4);
    int*            gstart  = (int*)  carve((N_GRAPHS + 1) * 4);
    (void)ws_size; (void)in_sizes; (void)n_in; (void)out_size;

    k_hist        <<<NCHUNK, 1024, 0, stream>>>(dst, hist);
    k_colscan     <<<NBUCK,  512,  0, stream>>>(hist, btot);
    k_bscan_gstart<<<2,      512,  0, stream>>>(btot, base, bat, gstart);
    k_partition   <<<NCHUNK, 1024, 0, stream>>>(src, dst, ea, hist, base, part);
    k_deg         <<<NBUCK,  512,  0, stream>>>(part, base, dinv, row_off);
    k_scat        <<<NBUCK,  512,  0, stream>>>(part, base, dinv, row_off, esec);

    k_gemm1<<<GB, 256, 0, stream>>>(x, W1, hbuf);
    k_agg<<<N_NODES / 16, 256, 0, stream>>>(hbuf, row_off, esec, dinv, b1, obuf);
    k_gemm<64><<<GB, 256, 0, stream>>>((const unsigned short*)obuf, W2, hbuf);
    k_agg<<<N_NODES / 16, 256, 0, stream>>>(hbuf, row_off, esec, dinv, b2, obuf);
    k_gemm<64><<<GB, 256, 0, stream>>>((const unsigned short*)obuf, W3, hbuf);
    k_agg<<<N_NODES / 16, 256, 0, stream>>>(hbuf, row_off, esec, dinv, b3, obuf);

    k_pool_linear<<<N_GRAPHS, 256, 0, stream>>>(obuf, gstart, Wl, bl, out);
}